// Round 1
// baseline (451.320 us; speedup 1.0000x reference)
//
#include <hip/hip_runtime.h>
#include <math.h>

#define EMB 30

__device__ __forceinline__ float leakyf(float x) { return x > 0.0f ? x : 0.1f * x; }

// insert v into descending-sorted t[5], keeping top-5 (branchless)
__device__ __forceinline__ void ins5(float t[5], float v) {
  t[4] = fmaxf(t[4], v);
  float a;
  a = fmaxf(t[3], t[4]); t[4] = fminf(t[3], t[4]); t[3] = a;
  a = fmaxf(t[2], t[3]); t[3] = fminf(t[2], t[3]); t[2] = a;
  a = fmaxf(t[1], t[2]); t[2] = fminf(t[1], t[2]); t[1] = a;
  a = fmaxf(t[0], t[1]); t[1] = fminf(t[0], t[1]); t[0] = a;
}

// a = top-5 of merge(a, b); both sorted descending.
// c[k] = max over {b[k], min(a[i], b[k-1-i]) for i=0..k-1, a[k]}
__device__ __forceinline__ void merge5(float a[5], const float b[5]) {
  float c0 = fmaxf(a[0], b[0]);
  float c1 = fmaxf(fmaxf(fminf(a[0], b[0]), a[1]), b[1]);
  float c2 = fmaxf(fmaxf(fminf(a[0], b[1]), fminf(a[1], b[0])), fmaxf(a[2], b[2]));
  float c3 = fmaxf(fmaxf(fminf(a[0], b[2]), fminf(a[1], b[1])),
                   fmaxf(fminf(a[2], b[0]), fmaxf(a[3], b[3])));
  float c4 = fmaxf(fmaxf(fmaxf(fminf(a[0], b[3]), fminf(a[1], b[2])),
                         fmaxf(fminf(a[2], b[1]), fminf(a[3], b[0]))),
                   fmaxf(a[4], b[4]));
  a[0] = c0; a[1] = c1; a[2] = c2; a[3] = c3; a[4] = c4;
}

// conv_resid per row + transposed raw/conv output + reciprocal norms
__global__ __launch_bounds__(256) void prep_kernel(
    const float* __restrict__ X, int L,
    const float* __restrict__ Wc, const float* __restrict__ bc,
    float* __restrict__ rawT, float* __restrict__ convT,
    float* __restrict__ rn_raw, float* __restrict__ rn_conv) {
  __shared__ float sW[EMB * EMB * 3];
  __shared__ float sb[EMB];
  int tid = threadIdx.x;
  for (int i = tid; i < EMB * EMB * 3; i += 256) sW[i] = Wc[i];
  if (tid < EMB) sb[tid] = bc[tid];
  __syncthreads();
  int l = blockIdx.x * 256 + tid;
  if (l >= L) return;
  float xm[EMB], x0[EMB], xp[EMB];
#pragma unroll
  for (int i = 0; i < EMB; ++i) x0[i] = X[(size_t)l * EMB + i];
#pragma unroll
  for (int i = 0; i < EMB; ++i) xm[i] = (l > 0) ? X[(size_t)(l - 1) * EMB + i] : 0.0f;
#pragma unroll
  for (int i = 0; i < EMB; ++i) xp[i] = (l < L - 1) ? X[(size_t)(l + 1) * EMB + i] : 0.0f;
  float sr = 0.0f;
#pragma unroll
  for (int i = 0; i < EMB; ++i) sr += x0[i] * x0[i];
  float sc = 0.0f;
#pragma unroll
  for (int o = 0; o < EMB; ++o) {
    float acc = sb[o];
#pragma unroll
    for (int i = 0; i < EMB; ++i) {
      acc += sW[o * 90 + i * 3 + 0] * xm[i];
      acc += sW[o * 90 + i * 3 + 1] * x0[i];
      acc += sW[o * 90 + i * 3 + 2] * xp[i];
    }
    float y = leakyf(acc) + x0[o];
    convT[(size_t)o * L + l] = y;
    rawT[(size_t)o * L + l] = x0[o];
    sc += y * y;
  }
  rn_raw[l] = 1.0f / sqrtf(sr);
  rn_conv[l] = 1.0f / sqrtf(sc);
}

// q_weights = softmax over Q of (q_conv . Wqw[0:30] + idf * Wqw[30]); one block
__global__ __launch_bounds__(1024) void qw_kernel(
    const float* __restrict__ qcT, const float* __restrict__ q_idfs,
    const float* __restrict__ Wqw, float* __restrict__ qw, int Q) {
  __shared__ float sW[EMB + 1];
  __shared__ float sredA[16], sredB[16];
  int tid = threadIdx.x;
  if (tid < EMB + 1) sW[tid] = Wqw[tid];
  __syncthreads();
  float lmax = -3.0e38f;
  for (int q = tid; q < Q; q += 1024) {
    float acc = q_idfs[q] * sW[EMB];
#pragma unroll
    for (int i = 0; i < EMB; ++i) acc += qcT[(size_t)i * Q + q] * sW[i];
    qw[q] = acc;
    lmax = fmaxf(lmax, acc);
  }
#pragma unroll
  for (int m = 1; m < 64; m <<= 1) lmax = fmaxf(lmax, __shfl_xor(lmax, m));
  if ((tid & 63) == 0) sredA[tid >> 6] = lmax;
  __syncthreads();
  float M = sredA[0];
  for (int w = 1; w < 16; ++w) M = fmaxf(M, sredA[w]);
  float lsum = 0.0f;
  for (int q = tid; q < Q; q += 1024) {
    float e = expf(qw[q] - M);
    qw[q] = e;
    lsum += e;
  }
#pragma unroll
  for (int m = 1; m < 64; m <<= 1) lsum += __shfl_xor(lsum, m);
  if ((tid & 63) == 0) sredB[tid >> 6] = lsum;
  __syncthreads();
  float S = 0.0f;
  for (int w = 0; w < 16; ++w) S += sredB[w];
  float rinv = 1.0f / S;
  for (int q = tid; q < Q; q += 1024) qw[q] *= rinv;
}

// 4 questions per block; top-5 + >0.999 count over both docs, raw+conv sims;
// then per-question 6->8->1 MLP scaled by softmax weight.
__global__ __launch_bounds__(256) void main_kernel(
    const float* __restrict__ d1rT, const float* __restrict__ d1cT,
    const float* __restrict__ d2rT, const float* __restrict__ d2cT,
    const float* __restrict__ qrT, const float* __restrict__ qcT,
    const float* __restrict__ rn1r, const float* __restrict__ rn1c,
    const float* __restrict__ rn2r, const float* __restrict__ rn2c,
    const float* __restrict__ rnqr, const float* __restrict__ rnqc,
    const float* __restrict__ qw,
    const float* __restrict__ W1, const float* __restrict__ W2,
    float* __restrict__ lo1, float* __restrict__ lo2,
    int Q, int D) {
  __shared__ float qsr[4][EMB], qsc[4][EMB];
  __shared__ float red[16][4][5];
  __shared__ int redc[8][4];
  __shared__ float finals[16][5];
  __shared__ int fcnt[8];
  int tid = threadIdx.x;
  int q0 = blockIdx.x * 4;
  if (tid < 120) { int qq = tid / 30, i = tid % 30; qsr[qq][i] = qrT[(size_t)i * Q + q0 + qq]; }
  if (tid >= 128 && tid < 248) {
    int u = tid - 128; int qq = u / 30, i = u % 30;
    qsc[qq][i] = qcT[(size_t)i * Q + q0 + qq];
  }
  __syncthreads();
  float rqr[4], rqc[4];
#pragma unroll
  for (int qq = 0; qq < 4; ++qq) { rqr[qq] = rnqr[q0 + qq]; rqc[qq] = rnqc[q0 + qq]; }
  float t[16][5];
#pragma unroll
  for (int li = 0; li < 16; ++li)
#pragma unroll
    for (int k = 0; k < 5; ++k) t[li][k] = -2.0f;
  int cnt[8];
#pragma unroll
  for (int ci = 0; ci < 8; ++ci) cnt[ci] = 0;

  for (int j = tid; j < D; j += 256) {
    float a[4][4];
#pragma unroll
    for (int qq = 0; qq < 4; ++qq)
#pragma unroll
      for (int ty = 0; ty < 4; ++ty) a[qq][ty] = 0.0f;
#pragma unroll
    for (int i = 0; i < EMB; ++i) {
      float v0 = d1rT[(size_t)i * D + j];
      float v1 = d1cT[(size_t)i * D + j];
      float v2 = d2rT[(size_t)i * D + j];
      float v3 = d2cT[(size_t)i * D + j];
#pragma unroll
      for (int qq = 0; qq < 4; ++qq) {
        a[qq][0] += qsr[qq][i] * v0;
        a[qq][1] += qsc[qq][i] * v1;
        a[qq][2] += qsr[qq][i] * v2;
        a[qq][3] += qsc[qq][i] * v3;
      }
    }
    float r1r = rn1r[j], r1c = rn1c[j], r2r = rn2r[j], r2c = rn2c[j];
#pragma unroll
    for (int qq = 0; qq < 4; ++qq) {
      float s0 = a[qq][0] * rqr[qq] * r1r;
      float s1 = a[qq][1] * rqc[qq] * r1c;
      float s2 = a[qq][2] * rqr[qq] * r2r;
      float s3 = a[qq][3] * rqc[qq] * r2c;
      cnt[qq * 2 + 0] += (s0 > 0.999f) ? 1 : 0;
      cnt[qq * 2 + 1] += (s2 > 0.999f) ? 1 : 0;
      ins5(t[qq * 4 + 0], s0);
      ins5(t[qq * 4 + 1], s1);
      ins5(t[qq * 4 + 2], s2);
      ins5(t[qq * 4 + 3], s3);
    }
  }
  // wave-level tree merge of sorted 5-lists + count reduce
#pragma unroll
  for (int m = 1; m < 64; m <<= 1) {
#pragma unroll
    for (int li = 0; li < 16; ++li) {
      float b[5];
#pragma unroll
      for (int k = 0; k < 5; ++k) b[k] = __shfl_xor(t[li][k], m);
      merge5(t[li], b);
    }
#pragma unroll
    for (int ci = 0; ci < 8; ++ci) cnt[ci] += __shfl_xor(cnt[ci], m);
  }
  int wave = tid >> 6;
  if ((tid & 63) == 0) {
#pragma unroll
    for (int li = 0; li < 16; ++li)
#pragma unroll
      for (int k = 0; k < 5; ++k) red[li][wave][k] = t[li][k];
#pragma unroll
    for (int ci = 0; ci < 8; ++ci) redc[ci][wave] = cnt[ci];
  }
  __syncthreads();
  if (tid < 16) {
    float aa[5];
#pragma unroll
    for (int k = 0; k < 5; ++k) aa[k] = red[tid][0][k];
    for (int w = 1; w < 4; ++w) {
      float b[5];
#pragma unroll
      for (int k = 0; k < 5; ++k) b[k] = red[tid][w][k];
      merge5(aa, b);
    }
#pragma unroll
    for (int k = 0; k < 5; ++k) finals[tid][k] = aa[k];
  }
  if (tid < 8) fcnt[tid] = redc[tid][0] + redc[tid][1] + redc[tid][2] + redc[tid][3];
  __syncthreads();
  if (tid < 8) {
    int qq = tid >> 1, d = tid & 1;
    int c = fcnt[qq * 2 + d];
    const float* Ti = finals[qq * 4 + d * 2 + 0];
    const float* Ts = finals[qq * 4 + d * 2 + 1];
    float tmp[6];
    tmp[0] = (c > 0) ? 1.0f : 0.0f;
    tmp[1] = fminf((float)c, 5.0f) * 0.2f;
    tmp[2] = Ti[0];
    tmp[3] = (Ti[0] + Ti[1] + Ti[2] + Ti[3] + Ti[4]) * 0.2f;
    tmp[4] = Ts[0];
    tmp[5] = (Ts[0] + Ts[1] + Ts[2] + Ts[3] + Ts[4]) * 0.2f;
    float lo = 0.0f;
#pragma unroll
    for (int r = 0; r < 8; ++r) {
      float h = 0.0f;
#pragma unroll
      for (int cidx = 0; cidx < 6; ++cidx) h += W1[r * 6 + cidx] * tmp[cidx];
      lo += W2[r] * leakyf(h);
    }
    float res = lo * qw[q0 + qq];
    if (d == 0) lo1[q0 + qq] = res; else lo2[q0 + qq] = res;
  }
}

__global__ __launch_bounds__(256) void final_kernel(
    const float* __restrict__ lo1, const float* __restrict__ lo2,
    const float* __restrict__ gaf, const float* __restrict__ baf,
    const float* __restrict__ Wout, float* __restrict__ out, int Q) {
  __shared__ float s1s[4], s2s[4];
  int tid = threadIdx.x;
  float s1 = 0.0f, s2 = 0.0f;
  for (int q = tid; q < Q; q += 256) { s1 += lo1[q]; s2 += lo2[q]; }
#pragma unroll
  for (int m = 1; m < 64; m <<= 1) { s1 += __shfl_xor(s1, m); s2 += __shfl_xor(s2, m); }
  if ((tid & 63) == 0) { s1s[tid >> 6] = s1; s2s[tid >> 6] = s2; }
  __syncthreads();
  if (tid == 0) {
    float S1 = s1s[0] + s1s[1] + s1s[2] + s1s[3];
    float S2 = s2s[0] + s2s[1] + s2s[2] + s2s[3];
    float e1 = S1 / (float)Q, e2 = S2 / (float)Q;
    float good = gaf[0] * Wout[0] + gaf[1] * Wout[1] + gaf[2] * Wout[2] + gaf[3] * Wout[3] + e1 * Wout[4];
    float bad  = baf[0] * Wout[0] + baf[1] * Wout[1] + baf[2] * Wout[2] + baf[3] * Wout[3] + e2 * Wout[4];
    float loss = fmaxf(0.0f, 1.0f + bad - good);
    out[0] = loss; out[1] = good; out[2] = bad;
  }
}

extern "C" void kernel_launch(void* const* d_in, const int* in_sizes, int n_in,
                              void* d_out, int out_size, void* d_ws, size_t ws_size,
                              hipStream_t stream) {
  const float* d1   = (const float*)d_in[0];
  const float* d2   = (const float*)d_in[1];
  const float* qe   = (const float*)d_in[2];
  const float* qidf = (const float*)d_in[3];
  const float* gaf  = (const float*)d_in[4];
  const float* baf  = (const float*)d_in[5];
  const float* Wc   = (const float*)d_in[6];
  const float* bc   = (const float*)d_in[7];
  const float* Wqw  = (const float*)d_in[8];
  const float* Wq1  = (const float*)d_in[9];
  const float* Wq2  = (const float*)d_in[10];
  const float* Wout = (const float*)d_in[11];
  int D = in_sizes[0] / EMB;
  int Q = in_sizes[2] / EMB;

  float* p = (float*)d_ws;
  float* d1rT = p; p += (size_t)EMB * D;
  float* d1cT = p; p += (size_t)EMB * D;
  float* d2rT = p; p += (size_t)EMB * D;
  float* d2cT = p; p += (size_t)EMB * D;
  float* qrT  = p; p += (size_t)EMB * Q;
  float* qcT  = p; p += (size_t)EMB * Q;
  float* rn1r = p; p += D;
  float* rn1c = p; p += D;
  float* rn2r = p; p += D;
  float* rn2c = p; p += D;
  float* rnqr = p; p += Q;
  float* rnqc = p; p += Q;
  float* qwv  = p; p += Q;
  float* lo1  = p; p += Q;
  float* lo2  = p; p += Q;

  prep_kernel<<<(Q + 255) / 256, 256, 0, stream>>>(qe, Q, Wc, bc, qrT, qcT, rnqr, rnqc);
  prep_kernel<<<(D + 255) / 256, 256, 0, stream>>>(d1, D, Wc, bc, d1rT, d1cT, rn1r, rn1c);
  prep_kernel<<<(D + 255) / 256, 256, 0, stream>>>(d2, D, Wc, bc, d2rT, d2cT, rn2r, rn2c);
  qw_kernel<<<1, 1024, 0, stream>>>(qcT, qidf, Wqw, qwv, Q);
  main_kernel<<<Q / 4, 256, 0, stream>>>(d1rT, d1cT, d2rT, d2cT, qrT, qcT,
                                         rn1r, rn1c, rn2r, rn2c, rnqr, rnqc,
                                         qwv, Wq1, Wq2, lo1, lo2, Q, D);
  final_kernel<<<1, 256, 0, stream>>>(lo1, lo2, gaf, baf, Wout, (float*)d_out, Q);
}

// Round 2
// 125.579 us; speedup vs baseline: 3.5939x; 3.5939x over previous
//
#include <hip/hip_runtime.h>
#include <hip/hip_bf16.h>
#include <math.h>

#define EMB 30

typedef __attribute__((ext_vector_type(8))) short bf16x8;
typedef __attribute__((ext_vector_type(4))) float f32x4;

__device__ __forceinline__ float leakyf(float x) { return x > 0.0f ? x : 0.1f * x; }

__device__ __forceinline__ unsigned short f2b(float x) {
  __hip_bfloat16 h = __float2bfloat16(x);
  union { __hip_bfloat16 h; unsigned short u; } cv;
  cv.h = h;
  return cv.u;
}

// insert v into descending-sorted t[5], keeping top-5 (branchless)
__device__ __forceinline__ void ins5(float (&t)[5], float v) {
  t[4] = fmaxf(t[4], v);
  float a;
  a = fmaxf(t[3], t[4]); t[4] = fminf(t[3], t[4]); t[3] = a;
  a = fmaxf(t[2], t[3]); t[3] = fminf(t[2], t[3]); t[2] = a;
  a = fmaxf(t[1], t[2]); t[2] = fminf(t[1], t[2]); t[1] = a;
  a = fmaxf(t[0], t[1]); t[1] = fminf(t[0], t[1]); t[0] = a;
}

// a = top-5 of merge(a, b); both sorted descending.
__device__ __forceinline__ void merge5(float (&a)[5], const float (&b)[5]) {
  float c0 = fmaxf(a[0], b[0]);
  float c1 = fmaxf(fmaxf(fminf(a[0], b[0]), a[1]), b[1]);
  float c2 = fmaxf(fmaxf(fminf(a[0], b[1]), fminf(a[1], b[0])), fmaxf(a[2], b[2]));
  float c3 = fmaxf(fmaxf(fminf(a[0], b[2]), fminf(a[1], b[1])),
                   fmaxf(fminf(a[2], b[0]), fmaxf(a[3], b[3])));
  float c4 = fmaxf(fmaxf(fmaxf(fminf(a[0], b[3]), fminf(a[1], b[2])),
                         fmaxf(fminf(a[2], b[1]), fminf(a[3], b[0]))),
                   fmaxf(a[4], b[4]));
  a[0] = c0; a[1] = c1; a[2] = c2; a[3] = c3; a[4] = c4;
}

// Per-row: trigram conv + leaky + residual; normalize raw & conv rows in fp32;
// emit bf16 [L][32] (K padded with zeros). Handles BOTH docs in one launch.
__global__ __launch_bounds__(256) void prep_doc_kernel(
    const float* __restrict__ X1, const float* __restrict__ X2, int L,
    const float* __restrict__ Wc, const float* __restrict__ bc,
    unsigned short* __restrict__ r1, unsigned short* __restrict__ c1,
    unsigned short* __restrict__ r2, unsigned short* __restrict__ c2) {
  __shared__ float sW[EMB * EMB * 3];
  __shared__ float sb[EMB];
  int tid = threadIdx.x;
  for (int i = tid; i < EMB * EMB * 3; i += 256) sW[i] = Wc[i];
  if (tid < EMB) sb[tid] = bc[tid];
  __syncthreads();
  int nb = gridDim.x >> 1;
  int doc = (blockIdx.x >= nb) ? 1 : 0;
  const float* X = doc ? X2 : X1;
  unsigned short* ro = doc ? r2 : r1;
  unsigned short* co = doc ? c2 : c1;
  int l = (blockIdx.x - doc * nb) * 256 + tid;
  if (l >= L) return;
  float xm[EMB], x0[EMB], xp[EMB], y[EMB];
#pragma unroll
  for (int i = 0; i < EMB; ++i) x0[i] = X[(size_t)l * EMB + i];
#pragma unroll
  for (int i = 0; i < EMB; ++i) xm[i] = (l > 0) ? X[(size_t)(l - 1) * EMB + i] : 0.0f;
#pragma unroll
  for (int i = 0; i < EMB; ++i) xp[i] = (l < L - 1) ? X[(size_t)(l + 1) * EMB + i] : 0.0f;
  float sr = 0.0f, sc = 0.0f;
#pragma unroll
  for (int i = 0; i < EMB; ++i) sr += x0[i] * x0[i];
#pragma unroll
  for (int o = 0; o < EMB; ++o) {
    float acc = sb[o];
#pragma unroll
    for (int i = 0; i < EMB; ++i) {
      acc += sW[o * 90 + i * 3 + 0] * xm[i];
      acc += sW[o * 90 + i * 3 + 1] * x0[i];
      acc += sW[o * 90 + i * 3 + 2] * xp[i];
    }
    float v = leakyf(acc) + x0[o];
    y[o] = v;
    sc += v * v;
  }
  float rnr = 1.0f / sqrtf(sr);
  float rnc = 1.0f / sqrtf(sc);
  unsigned int rp[16], cp[16];
#pragma unroll
  for (int k = 0; k < 15; ++k) {
    rp[k] = (unsigned int)f2b(x0[2 * k] * rnr) | ((unsigned int)f2b(x0[2 * k + 1] * rnr) << 16);
    cp[k] = (unsigned int)f2b(y[2 * k] * rnc) | ((unsigned int)f2b(y[2 * k + 1] * rnc) << 16);
  }
  rp[15] = 0u; cp[15] = 0u;
  unsigned int* rw = (unsigned int*)(ro + (size_t)l * 32);
  unsigned int* cw = (unsigned int*)(co + (size_t)l * 32);
#pragma unroll
  for (int k = 0; k < 16; ++k) { rw[k] = rp[k]; cw[k] = cp[k]; }
}

// Same for questions + softmax logit (uses UNNORMALIZED conv output).
__global__ __launch_bounds__(256) void prep_q_kernel(
    const float* __restrict__ X, int L,
    const float* __restrict__ Wc, const float* __restrict__ bc,
    const float* __restrict__ q_idfs, const float* __restrict__ Wqw,
    unsigned short* __restrict__ ro, unsigned short* __restrict__ co,
    float* __restrict__ logits) {
  __shared__ float sW[EMB * EMB * 3];
  __shared__ float sb[EMB];
  __shared__ float sQ[EMB + 1];
  int tid = threadIdx.x;
  for (int i = tid; i < EMB * EMB * 3; i += 256) sW[i] = Wc[i];
  if (tid < EMB) sb[tid] = bc[tid];
  if (tid < EMB + 1) sQ[tid] = Wqw[tid];
  __syncthreads();
  int l = blockIdx.x * 256 + tid;
  if (l >= L) return;
  float xm[EMB], x0[EMB], xp[EMB], y[EMB];
#pragma unroll
  for (int i = 0; i < EMB; ++i) x0[i] = X[(size_t)l * EMB + i];
#pragma unroll
  for (int i = 0; i < EMB; ++i) xm[i] = (l > 0) ? X[(size_t)(l - 1) * EMB + i] : 0.0f;
#pragma unroll
  for (int i = 0; i < EMB; ++i) xp[i] = (l < L - 1) ? X[(size_t)(l + 1) * EMB + i] : 0.0f;
  float sr = 0.0f, sc = 0.0f, lg = q_idfs[l] * sQ[EMB];
#pragma unroll
  for (int i = 0; i < EMB; ++i) sr += x0[i] * x0[i];
#pragma unroll
  for (int o = 0; o < EMB; ++o) {
    float acc = sb[o];
#pragma unroll
    for (int i = 0; i < EMB; ++i) {
      acc += sW[o * 90 + i * 3 + 0] * xm[i];
      acc += sW[o * 90 + i * 3 + 1] * x0[i];
      acc += sW[o * 90 + i * 3 + 2] * xp[i];
    }
    float v = leakyf(acc) + x0[o];
    y[o] = v;
    sc += v * v;
    lg += v * sQ[o];
  }
  logits[l] = lg;
  float rnr = 1.0f / sqrtf(sr);
  float rnc = 1.0f / sqrtf(sc);
  unsigned int rp[16], cp[16];
#pragma unroll
  for (int k = 0; k < 15; ++k) {
    rp[k] = (unsigned int)f2b(x0[2 * k] * rnr) | ((unsigned int)f2b(x0[2 * k + 1] * rnr) << 16);
    cp[k] = (unsigned int)f2b(y[2 * k] * rnc) | ((unsigned int)f2b(y[2 * k + 1] * rnc) << 16);
  }
  rp[15] = 0u; cp[15] = 0u;
  unsigned int* rw = (unsigned int*)(ro + (size_t)l * 32);
  unsigned int* cw = (unsigned int*)(co + (size_t)l * 32);
#pragma unroll
  for (int k = 0; k < 16; ++k) { rw[k] = rp[k]; cw[k] = cp[k]; }
}

// softmax over Q logits; one block
__global__ __launch_bounds__(1024) void qw_kernel(
    const float* __restrict__ logits, float* __restrict__ qw, int Q) {
  __shared__ float sredA[16], sredB[16];
  int tid = threadIdx.x;
  float lmax = -3.0e38f;
  for (int q = tid; q < Q; q += 1024) lmax = fmaxf(lmax, logits[q]);
#pragma unroll
  for (int m = 1; m < 64; m <<= 1) lmax = fmaxf(lmax, __shfl_xor(lmax, m));
  if ((tid & 63) == 0) sredA[tid >> 6] = lmax;
  __syncthreads();
  float M = sredA[0];
  for (int w = 1; w < 16; ++w) M = fmaxf(M, sredA[w]);
  float lsum = 0.0f;
  for (int q = tid; q < Q; q += 1024) {
    float e = expf(logits[q] - M);
    qw[q] = e;
    lsum += e;
  }
#pragma unroll
  for (int m = 1; m < 64; m <<= 1) lsum += __shfl_xor(lsum, m);
  if ((tid & 63) == 0) sredB[tid >> 6] = lsum;
  __syncthreads();
  float S = 0.0f;
  for (int w = 0; w < 16; ++w) S += sredB[w];
  float rinv = 1.0f / S;
  for (int q = tid; q < Q; q += 1024) qw[q] *= rinv;
}

// MFMA sims + per-lane top-5 + butterfly merge + cross-wave LDS merge.
// Block = 4 waves; blockIdx = (q_tile<<2) | d_split. Wave w covers D/16 j's.
__global__ __launch_bounds__(256) void main_kernel(
    const unsigned short* __restrict__ qrA, const unsigned short* __restrict__ qcA,
    const unsigned short* __restrict__ d1r, const unsigned short* __restrict__ d1c,
    const unsigned short* __restrict__ d2r, const unsigned short* __restrict__ d2c,
    float* __restrict__ partials, int Q, int D) {
  __shared__ float sm[4][16][22];
  int tid = threadIdx.x;
  int wave = tid >> 6, lane = tid & 63;
  int lo = lane & 15, hi = lane >> 4;
  int qt = blockIdx.x >> 2, ds = blockIdx.x & 3;
  int qrow = qt * 16 + lo;
  bf16x8 aR = *(const bf16x8*)(qrA + (size_t)qrow * 32 + hi * 8);
  bf16x8 aC = *(const bf16x8*)(qcA + (size_t)qrow * 32 + hi * 8);
  int chunk = D >> 4;            // j's per wave
  int j0 = (ds * 4 + wave) * chunk;
  int nt = chunk >> 4;           // 16-j tiles per wave
  float t[4][4][5];
  float cnt[4][2];
#pragma unroll
  for (int r = 0; r < 4; ++r) {
    cnt[r][0] = 0.0f; cnt[r][1] = 0.0f;
#pragma unroll
    for (int li = 0; li < 4; ++li)
#pragma unroll
      for (int k = 0; k < 5; ++k) t[r][li][k] = -2.0f;
  }
  size_t off = (size_t)(j0 + lo) * 32 + (size_t)hi * 8;
  for (int it = 0; it < nt; ++it, off += 512) {
    bf16x8 b0 = *(const bf16x8*)(d1r + off);
    bf16x8 b1 = *(const bf16x8*)(d1c + off);
    bf16x8 b2 = *(const bf16x8*)(d2r + off);
    bf16x8 b3 = *(const bf16x8*)(d2c + off);
    f32x4 z = {0.0f, 0.0f, 0.0f, 0.0f};
    f32x4 s0 = __builtin_amdgcn_mfma_f32_16x16x32_bf16(aR, b0, z, 0, 0, 0);
    f32x4 s1 = __builtin_amdgcn_mfma_f32_16x16x32_bf16(aC, b1, z, 0, 0, 0);
    f32x4 s2 = __builtin_amdgcn_mfma_f32_16x16x32_bf16(aR, b2, z, 0, 0, 0);
    f32x4 s3 = __builtin_amdgcn_mfma_f32_16x16x32_bf16(aC, b3, z, 0, 0, 0);
#pragma unroll
    for (int r = 0; r < 4; ++r) {
      cnt[r][0] += (s0[r] > 0.999f) ? 1.0f : 0.0f;
      cnt[r][1] += (s2[r] > 0.999f) ? 1.0f : 0.0f;
      ins5(t[r][0], s0[r]);
      ins5(t[r][1], s1[r]);
      ins5(t[r][2], s2[r]);
      ins5(t[r][3], s3[r]);
    }
  }
  // butterfly merge across the 16 j-lanes (same hi group holds same 4 q-rows)
#pragma unroll
  for (int m = 1; m < 16; m <<= 1) {
#pragma unroll
    for (int r = 0; r < 4; ++r) {
#pragma unroll
      for (int li = 0; li < 4; ++li) {
        float b[5];
#pragma unroll
        for (int k = 0; k < 5; ++k) b[k] = __shfl_xor(t[r][li][k], m);
        merge5(t[r][li], b);
      }
      cnt[r][0] += __shfl_xor(cnt[r][0], m);
      cnt[r][1] += __shfl_xor(cnt[r][1], m);
    }
  }
  if (lo == 0) {
#pragma unroll
    for (int r = 0; r < 4; ++r) {
      int qm = hi * 4 + r;
#pragma unroll
      for (int li = 0; li < 4; ++li)
#pragma unroll
        for (int k = 0; k < 5; ++k) sm[wave][qm][li * 5 + k] = t[r][li][k];
      sm[wave][qm][20] = cnt[r][0];
      sm[wave][qm][21] = cnt[r][1];
    }
  }
  __syncthreads();
  if (tid < 16) {
    float T[4][5];
    float c1, c2;
#pragma unroll
    for (int li = 0; li < 4; ++li)
#pragma unroll
      for (int k = 0; k < 5; ++k) T[li][k] = sm[0][tid][li * 5 + k];
    c1 = sm[0][tid][20];
    c2 = sm[0][tid][21];
#pragma unroll
    for (int w = 1; w < 4; ++w) {
#pragma unroll
      for (int li = 0; li < 4; ++li) {
        float b[5];
#pragma unroll
        for (int k = 0; k < 5; ++k) b[k] = sm[w][tid][li * 5 + k];
        merge5(T[li], b);
      }
      c1 += sm[w][tid][20];
      c2 += sm[w][tid][21];
    }
    float* dst = partials + ((size_t)(qt * 16 + tid) * 4 + ds) * 22;
#pragma unroll
    for (int li = 0; li < 4; ++li)
#pragma unroll
      for (int k = 0; k < 5; ++k) dst[li * 5 + k] = T[li][k];
    dst[20] = c1;
    dst[21] = c2;
  }
}

// Per question: merge 4 D-split partials, build 6-dim pools, MLP, scale by softmax weight.
__global__ __launch_bounds__(256) void stage2_kernel(
    const float* __restrict__ partials, const float* __restrict__ qwv,
    const float* __restrict__ W1, const float* __restrict__ W2,
    float* __restrict__ lo1, float* __restrict__ lo2, int Q) {
  int q = blockIdx.x * 256 + threadIdx.x;
  if (q >= Q) return;
  const float* p = partials + (size_t)q * 4 * 22;
  float T[4][5];
  float c1, c2;
#pragma unroll
  for (int li = 0; li < 4; ++li)
#pragma unroll
    for (int k = 0; k < 5; ++k) T[li][k] = p[li * 5 + k];
  c1 = p[20];
  c2 = p[21];
#pragma unroll
  for (int s = 1; s < 4; ++s) {
    const float* b0 = p + s * 22;
#pragma unroll
    for (int li = 0; li < 4; ++li) {
      float b[5];
#pragma unroll
      for (int k = 0; k < 5; ++k) b[k] = b0[li * 5 + k];
      merge5(T[li], b);
    }
    c1 += b0[20];
    c2 += b0[21];
  }
  float w = qwv[q];
#pragma unroll
  for (int d = 0; d < 2; ++d) {
    float c = d ? c2 : c1;
    const float (&Ti)[5] = T[d ? 2 : 0];
    const float (&Ts)[5] = T[d ? 3 : 1];
    float tmp[6];
    tmp[0] = (c > 0.0f) ? 1.0f : 0.0f;
    tmp[1] = fminf(c, 5.0f) * 0.2f;
    tmp[2] = Ti[0];
    tmp[3] = (Ti[0] + Ti[1] + Ti[2] + Ti[3] + Ti[4]) * 0.2f;
    tmp[4] = Ts[0];
    tmp[5] = (Ts[0] + Ts[1] + Ts[2] + Ts[3] + Ts[4]) * 0.2f;
    float lo = 0.0f;
#pragma unroll
    for (int r = 0; r < 8; ++r) {
      float h = 0.0f;
#pragma unroll
      for (int cidx = 0; cidx < 6; ++cidx) h += W1[r * 6 + cidx] * tmp[cidx];
      lo += W2[r] * leakyf(h);
    }
    if (d == 0) lo1[q] = lo * w; else lo2[q] = lo * w;
  }
}

__global__ __launch_bounds__(256) void final_kernel(
    const float* __restrict__ lo1, const float* __restrict__ lo2,
    const float* __restrict__ gaf, const float* __restrict__ baf,
    const float* __restrict__ Wout, float* __restrict__ out, int Q) {
  __shared__ float s1s[4], s2s[4];
  int tid = threadIdx.x;
  float s1 = 0.0f, s2 = 0.0f;
  for (int q = tid; q < Q; q += 256) { s1 += lo1[q]; s2 += lo2[q]; }
#pragma unroll
  for (int m = 1; m < 64; m <<= 1) { s1 += __shfl_xor(s1, m); s2 += __shfl_xor(s2, m); }
  if ((tid & 63) == 0) { s1s[tid >> 6] = s1; s2s[tid >> 6] = s2; }
  __syncthreads();
  if (tid == 0) {
    float S1 = s1s[0] + s1s[1] + s1s[2] + s1s[3];
    float S2 = s2s[0] + s2s[1] + s2s[2] + s2s[3];
    float e1 = S1 / (float)Q, e2 = S2 / (float)Q;
    float good = gaf[0] * Wout[0] + gaf[1] * Wout[1] + gaf[2] * Wout[2] + gaf[3] * Wout[3] + e1 * Wout[4];
    float bad  = baf[0] * Wout[0] + baf[1] * Wout[1] + baf[2] * Wout[2] + baf[3] * Wout[3] + e2 * Wout[4];
    float loss = fmaxf(0.0f, 1.0f + bad - good);
    out[0] = loss; out[1] = good; out[2] = bad;
  }
}

extern "C" void kernel_launch(void* const* d_in, const int* in_sizes, int n_in,
                              void* d_out, int out_size, void* d_ws, size_t ws_size,
                              hipStream_t stream) {
  const float* d1   = (const float*)d_in[0];
  const float* d2   = (const float*)d_in[1];
  const float* qe   = (const float*)d_in[2];
  const float* qidf = (const float*)d_in[3];
  const float* gaf  = (const float*)d_in[4];
  const float* baf  = (const float*)d_in[5];
  const float* Wc   = (const float*)d_in[6];
  const float* bc   = (const float*)d_in[7];
  const float* Wqw  = (const float*)d_in[8];
  const float* Wq1  = (const float*)d_in[9];
  const float* Wq2  = (const float*)d_in[10];
  const float* Wout = (const float*)d_in[11];
  int D = in_sizes[0] / EMB;
  int Q = in_sizes[2] / EMB;

  unsigned short* us = (unsigned short*)d_ws;
  unsigned short* d1r = us; us += (size_t)D * 32;
  unsigned short* d1c = us; us += (size_t)D * 32;
  unsigned short* d2r = us; us += (size_t)D * 32;
  unsigned short* d2c = us; us += (size_t)D * 32;
  unsigned short* qrA = us; us += (size_t)Q * 32;
  unsigned short* qcA = us; us += (size_t)Q * 32;
  float* fp = (float*)us;
  float* logits   = fp; fp += Q;
  float* qwv      = fp; fp += Q;
  float* lo1      = fp; fp += Q;
  float* lo2      = fp; fp += Q;
  float* partials = fp; fp += (size_t)Q * 4 * 22;

  int nbD = (D + 255) / 256;
  prep_doc_kernel<<<2 * nbD, 256, 0, stream>>>(d1, d2, D, Wc, bc, d1r, d1c, d2r, d2c);
  prep_q_kernel<<<(Q + 255) / 256, 256, 0, stream>>>(qe, Q, Wc, bc, qidf, Wqw, qrA, qcA, logits);
  qw_kernel<<<1, 1024, 0, stream>>>(logits, qwv, Q);
  main_kernel<<<(Q / 16) * 4, 256, 0, stream>>>(qrA, qcA, d1r, d1c, d2r, d2c, partials, Q, D);
  stage2_kernel<<<(Q + 255) / 256, 256, 0, stream>>>(partials, qwv, Wq1, Wq2, lo1, lo2, Q);
  final_kernel<<<1, 256, 0, stream>>>(lo1, lo2, gaf, baf, Wout, (float*)d_out, Q);
}

// Round 3
// 94.721 us; speedup vs baseline: 4.7648x; 1.3258x over previous
//
#include <hip/hip_runtime.h>
#include <hip/hip_bf16.h>
#include <math.h>

#define EMB 30

typedef __attribute__((ext_vector_type(8))) short bf16x8;
typedef __attribute__((ext_vector_type(4))) float f32x4;

__device__ __forceinline__ float leakyf(float x) { return x > 0.0f ? x : 0.1f * x; }

__device__ __forceinline__ unsigned short f2b(float x) {
  __hip_bfloat16 h = __float2bfloat16(x);
  union { __hip_bfloat16 h; unsigned short u; } cv;
  cv.h = h;
  return cv.u;
}

// insert v into descending-sorted t[5], keeping top-5 (branchless)
__device__ __forceinline__ void ins5(float (&t)[5], float v) {
  t[4] = fmaxf(t[4], v);
  float a;
  a = fmaxf(t[3], t[4]); t[4] = fminf(t[3], t[4]); t[3] = a;
  a = fmaxf(t[2], t[3]); t[3] = fminf(t[2], t[3]); t[2] = a;
  a = fmaxf(t[1], t[2]); t[2] = fminf(t[1], t[2]); t[1] = a;
  a = fmaxf(t[0], t[1]); t[1] = fminf(t[0], t[1]); t[0] = a;
}

// a = top-5 of merge(a, b); both sorted descending.
__device__ __forceinline__ void merge5(float (&a)[5], const float (&b)[5]) {
  float c0 = fmaxf(a[0], b[0]);
  float c1 = fmaxf(fmaxf(fminf(a[0], b[0]), a[1]), b[1]);
  float c2 = fmaxf(fmaxf(fminf(a[0], b[1]), fminf(a[1], b[0])), fmaxf(a[2], b[2]));
  float c3 = fmaxf(fmaxf(fminf(a[0], b[2]), fminf(a[1], b[1])),
                   fmaxf(fminf(a[2], b[0]), fmaxf(a[3], b[3])));
  float c4 = fmaxf(fmaxf(fmaxf(fminf(a[0], b[3]), fminf(a[1], b[2])),
                         fmaxf(fminf(a[2], b[1]), fminf(a[3], b[0]))),
                   fmaxf(a[4], b[4]));
  a[0] = c0; a[1] = c1; a[2] = c2; a[3] = c3; a[4] = c4;
}

// Fused prep for questions + both docs. Block = 256 threads = 256 rows of one
// source. Input slab staged in LDS (coalesced); conv weights via uniform
// scalar loads (SGPR operands). Emits normalized bf16 [L][32] raw+conv, and
// softmax logits for q rows.
__global__ __launch_bounds__(256) void prep_all_kernel(
    const float* __restrict__ Xq, const float* __restrict__ X1,
    const float* __restrict__ X2, int Q, int D,
    const float* __restrict__ Wc, const float* __restrict__ bc,
    const float* __restrict__ qidf, const float* __restrict__ Wqw,
    unsigned short* __restrict__ qr, unsigned short* __restrict__ qc,
    unsigned short* __restrict__ d1r, unsigned short* __restrict__ d1c,
    unsigned short* __restrict__ d2r, unsigned short* __restrict__ d2c,
    float* __restrict__ logits) {
  __shared__ float sX[258 * EMB];
  int tid = threadIdx.x;
  int nbQ = Q >> 8, nbD = D >> 8;
  int b = blockIdx.x;
  const float* X;
  unsigned short *ro, *co;
  int L, l0;
  bool isQ = false;
  if (b < nbQ) { X = Xq; ro = qr; co = qc; L = Q; l0 = b << 8; isQ = true; }
  else if (b < nbQ + nbD) { X = X1; ro = d1r; co = d1c; L = D; l0 = (b - nbQ) << 8; }
  else { X = X2; ro = d2r; co = d2c; L = D; l0 = (b - nbQ - nbD) << 8; }

  int base = l0 * EMB - EMB;          // row l0-1 start
  int lim = L * EMB;
  for (int idx = tid; idx < 258 * EMB; idx += 256) {
    int g = base + idx;
    sX[idx] = (g >= 0 && g < lim) ? X[g] : 0.0f;
  }
  __syncthreads();

  int l = l0 + tid;                    // L is a multiple of 256
  float xm[EMB], x0[EMB], xp[EMB], y[EMB];
#pragma unroll
  for (int i = 0; i < EMB; ++i) xm[i] = sX[tid * EMB + i];
#pragma unroll
  for (int i = 0; i < EMB; ++i) x0[i] = sX[(tid + 1) * EMB + i];
#pragma unroll
  for (int i = 0; i < EMB; ++i) xp[i] = sX[(tid + 2) * EMB + i];

  float sr = 0.0f, sc = 0.0f, lg = 0.0f;
#pragma unroll
  for (int i = 0; i < EMB; ++i) sr += x0[i] * x0[i];
#pragma unroll 1
  for (int o = 0; o < EMB; ++o) {
    float acc = bc[o];                 // uniform -> scalar load
#pragma unroll
    for (int i = 0; i < EMB; ++i) {
      acc += Wc[o * 90 + i * 3 + 0] * xm[i];   // uniform -> s_load
      acc += Wc[o * 90 + i * 3 + 1] * x0[i];
      acc += Wc[o * 90 + i * 3 + 2] * xp[i];
    }
    float v = leakyf(acc) + x0[o];
    y[o] = v;
    sc += v * v;
    lg += v * Wqw[o];                  // uniform -> scalar load
  }
  float rnr = 1.0f / sqrtf(sr);
  float rnc = 1.0f / sqrtf(sc);
  if (isQ) logits[l] = lg + qidf[l] * Wqw[EMB];

  unsigned int rp[16], cp[16];
#pragma unroll
  for (int k = 0; k < 15; ++k) {
    rp[k] = (unsigned int)f2b(x0[2 * k] * rnr) | ((unsigned int)f2b(x0[2 * k + 1] * rnr) << 16);
    cp[k] = (unsigned int)f2b(y[2 * k] * rnc) | ((unsigned int)f2b(y[2 * k + 1] * rnc) << 16);
  }
  rp[15] = 0u; cp[15] = 0u;
  unsigned int* rw = (unsigned int*)(ro + (size_t)l * 32);
  unsigned int* cw = (unsigned int*)(co + (size_t)l * 32);
#pragma unroll
  for (int k = 0; k < 16; ++k) { rw[k] = rp[k]; cw[k] = cp[k]; }
}

// MFMA sims + per-lane top-5 + butterfly merge + cross-wave LDS merge.
// Block = 4 waves; blockIdx = (q_tile<<2) | d_split. Wave w covers D/16 j's.
__global__ __launch_bounds__(256) void main_kernel(
    const unsigned short* __restrict__ qrA, const unsigned short* __restrict__ qcA,
    const unsigned short* __restrict__ d1r, const unsigned short* __restrict__ d1c,
    const unsigned short* __restrict__ d2r, const unsigned short* __restrict__ d2c,
    float* __restrict__ partials, int Q, int D) {
  __shared__ float sm[4][16][22];
  int tid = threadIdx.x;
  int wave = tid >> 6, lane = tid & 63;
  int lo = lane & 15, hi = lane >> 4;
  int qt = blockIdx.x >> 2, ds = blockIdx.x & 3;
  int qrow = qt * 16 + lo;
  bf16x8 aR = *(const bf16x8*)(qrA + (size_t)qrow * 32 + hi * 8);
  bf16x8 aC = *(const bf16x8*)(qcA + (size_t)qrow * 32 + hi * 8);
  int chunk = D >> 4;            // j's per wave
  int j0 = (ds * 4 + wave) * chunk;
  int nt = chunk >> 4;           // 16-j tiles per wave
  float t[4][4][5];
  float cnt[4][2];
#pragma unroll
  for (int r = 0; r < 4; ++r) {
    cnt[r][0] = 0.0f; cnt[r][1] = 0.0f;
#pragma unroll
    for (int li = 0; li < 4; ++li)
#pragma unroll
      for (int k = 0; k < 5; ++k) t[r][li][k] = -2.0f;
  }
  size_t off = (size_t)(j0 + lo) * 32 + (size_t)hi * 8;
  for (int it = 0; it < nt; ++it, off += 512) {
    bf16x8 b0 = *(const bf16x8*)(d1r + off);
    bf16x8 b1 = *(const bf16x8*)(d1c + off);
    bf16x8 b2 = *(const bf16x8*)(d2r + off);
    bf16x8 b3 = *(const bf16x8*)(d2c + off);
    f32x4 z = {0.0f, 0.0f, 0.0f, 0.0f};
    f32x4 s0 = __builtin_amdgcn_mfma_f32_16x16x32_bf16(aR, b0, z, 0, 0, 0);
    f32x4 s1 = __builtin_amdgcn_mfma_f32_16x16x32_bf16(aC, b1, z, 0, 0, 0);
    f32x4 s2 = __builtin_amdgcn_mfma_f32_16x16x32_bf16(aR, b2, z, 0, 0, 0);
    f32x4 s3 = __builtin_amdgcn_mfma_f32_16x16x32_bf16(aC, b3, z, 0, 0, 0);
#pragma unroll
    for (int r = 0; r < 4; ++r) {
      cnt[r][0] += (s0[r] > 0.999f) ? 1.0f : 0.0f;
      cnt[r][1] += (s2[r] > 0.999f) ? 1.0f : 0.0f;
      ins5(t[r][0], s0[r]);
      ins5(t[r][1], s1[r]);
      ins5(t[r][2], s2[r]);
      ins5(t[r][3], s3[r]);
    }
  }
  // butterfly merge across the 16 j-lanes (same hi group holds same 4 q-rows)
#pragma unroll
  for (int m = 1; m < 16; m <<= 1) {
#pragma unroll
    for (int r = 0; r < 4; ++r) {
#pragma unroll
      for (int li = 0; li < 4; ++li) {
        float b[5];
#pragma unroll
        for (int k = 0; k < 5; ++k) b[k] = __shfl_xor(t[r][li][k], m);
        merge5(t[r][li], b);
      }
      cnt[r][0] += __shfl_xor(cnt[r][0], m);
      cnt[r][1] += __shfl_xor(cnt[r][1], m);
    }
  }
  if (lo == 0) {
#pragma unroll
    for (int r = 0; r < 4; ++r) {
      int qm = hi * 4 + r;
#pragma unroll
      for (int li = 0; li < 4; ++li)
#pragma unroll
        for (int k = 0; k < 5; ++k) sm[wave][qm][li * 5 + k] = t[r][li][k];
      sm[wave][qm][20] = cnt[r][0];
      sm[wave][qm][21] = cnt[r][1];
    }
  }
  __syncthreads();
  if (tid < 16) {
    float T[4][5];
    float c1, c2;
#pragma unroll
    for (int li = 0; li < 4; ++li)
#pragma unroll
      for (int k = 0; k < 5; ++k) T[li][k] = sm[0][tid][li * 5 + k];
    c1 = sm[0][tid][20];
    c2 = sm[0][tid][21];
#pragma unroll
    for (int w = 1; w < 4; ++w) {
#pragma unroll
      for (int li = 0; li < 4; ++li) {
        float b[5];
#pragma unroll
        for (int k = 0; k < 5; ++k) b[k] = sm[w][tid][li * 5 + k];
        merge5(T[li], b);
      }
      c1 += sm[w][tid][20];
      c2 += sm[w][tid][21];
    }
    float* dst = partials + ((size_t)(qt * 16 + tid) * 4 + ds) * 22;
#pragma unroll
    for (int li = 0; li < 4; ++li)
#pragma unroll
      for (int k = 0; k < 5; ++k) dst[li * 5 + k] = T[li][k];
    dst[20] = c1;
    dst[21] = c2;
  }
}

// Single block: softmax over logits + per-q merge of 4 D-split partials +
// 6->8->1 MLP + weighted sum + final good/bad/loss outputs.
__global__ __launch_bounds__(1024) void stage2_final_kernel(
    const float* __restrict__ logits, const float* __restrict__ partials,
    const float* __restrict__ W1, const float* __restrict__ W2,
    const float* __restrict__ gaf, const float* __restrict__ baf,
    const float* __restrict__ Wout, float* __restrict__ out, int Q) {
  __shared__ float sred[16];
  int tid = threadIdx.x;
  int lane = tid & 63, wave = tid >> 6;

  // softmax max
  float lmax = -3.0e38f;
  for (int q = tid; q < Q; q += 1024) lmax = fmaxf(lmax, logits[q]);
#pragma unroll
  for (int m = 1; m < 64; m <<= 1) lmax = fmaxf(lmax, __shfl_xor(lmax, m));
  if (lane == 0) sred[wave] = lmax;
  __syncthreads();
  float M = sred[0];
#pragma unroll
  for (int w = 1; w < 16; ++w) M = fmaxf(M, sred[w]);
  __syncthreads();
  // softmax sum
  float lsum = 0.0f;
  for (int q = tid; q < Q; q += 1024) lsum += expf(logits[q] - M);
#pragma unroll
  for (int m = 1; m < 64; m <<= 1) lsum += __shfl_xor(lsum, m);
  if (lane == 0) sred[wave] = lsum;
  __syncthreads();
  float S = 0.0f;
#pragma unroll
  for (int w = 0; w < 16; ++w) S += sred[w];
  float rS = 1.0f / S;
  __syncthreads();

  // per-q: merge 4 splits, pools, MLP, weight
  float s1 = 0.0f, s2 = 0.0f;
  for (int q = tid; q < Q; q += 1024) {
    const float* p = partials + (size_t)q * 4 * 22;
    float T[4][5];
    float c1, c2;
#pragma unroll
    for (int li = 0; li < 4; ++li)
#pragma unroll
      for (int k = 0; k < 5; ++k) T[li][k] = p[li * 5 + k];
    c1 = p[20];
    c2 = p[21];
#pragma unroll
    for (int s = 1; s < 4; ++s) {
      const float* b0 = p + s * 22;
#pragma unroll
      for (int li = 0; li < 4; ++li) {
        float b[5];
#pragma unroll
        for (int k = 0; k < 5; ++k) b[k] = b0[li * 5 + k];
        merge5(T[li], b);
      }
      c1 += b0[20];
      c2 += b0[21];
    }
    float w = expf(logits[q] - M) * rS;
#pragma unroll
    for (int d = 0; d < 2; ++d) {
      float c = d ? c2 : c1;
      const float (&Ti)[5] = T[d ? 2 : 0];
      const float (&Ts)[5] = T[d ? 3 : 1];
      float tmp[6];
      tmp[0] = (c > 0.0f) ? 1.0f : 0.0f;
      tmp[1] = fminf(c, 5.0f) * 0.2f;
      tmp[2] = Ti[0];
      tmp[3] = (Ti[0] + Ti[1] + Ti[2] + Ti[3] + Ti[4]) * 0.2f;
      tmp[4] = Ts[0];
      tmp[5] = (Ts[0] + Ts[1] + Ts[2] + Ts[3] + Ts[4]) * 0.2f;
      float lo = 0.0f;
#pragma unroll
      for (int r = 0; r < 8; ++r) {
        float h = 0.0f;
#pragma unroll
        for (int cidx = 0; cidx < 6; ++cidx) h += W1[r * 6 + cidx] * tmp[cidx];
        lo += W2[r] * leakyf(h);
      }
      if (d == 0) s1 += lo * w; else s2 += lo * w;
    }
  }
  // block reduce s1, s2
  __shared__ float r1[16], r2[16];
#pragma unroll
  for (int m = 1; m < 64; m <<= 1) { s1 += __shfl_xor(s1, m); s2 += __shfl_xor(s2, m); }
  if (lane == 0) { r1[wave] = s1; r2[wave] = s2; }
  __syncthreads();
  if (tid == 0) {
    float S1 = 0.0f, S2 = 0.0f;
#pragma unroll
    for (int w = 0; w < 16; ++w) { S1 += r1[w]; S2 += r2[w]; }
    float e1 = S1 / (float)Q, e2 = S2 / (float)Q;
    float good = gaf[0] * Wout[0] + gaf[1] * Wout[1] + gaf[2] * Wout[2] + gaf[3] * Wout[3] + e1 * Wout[4];
    float bad  = baf[0] * Wout[0] + baf[1] * Wout[1] + baf[2] * Wout[2] + baf[3] * Wout[3] + e2 * Wout[4];
    float loss = fmaxf(0.0f, 1.0f + bad - good);
    out[0] = loss; out[1] = good; out[2] = bad;
  }
}

extern "C" void kernel_launch(void* const* d_in, const int* in_sizes, int n_in,
                              void* d_out, int out_size, void* d_ws, size_t ws_size,
                              hipStream_t stream) {
  const float* d1   = (const float*)d_in[0];
  const float* d2   = (const float*)d_in[1];
  const float* qe   = (const float*)d_in[2];
  const float* qidf = (const float*)d_in[3];
  const float* gaf  = (const float*)d_in[4];
  const float* baf  = (const float*)d_in[5];
  const float* Wc   = (const float*)d_in[6];
  const float* bc   = (const float*)d_in[7];
  const float* Wqw  = (const float*)d_in[8];
  const float* Wq1  = (const float*)d_in[9];
  const float* Wq2  = (const float*)d_in[10];
  const float* Wout = (const float*)d_in[11];
  int D = in_sizes[0] / EMB;
  int Q = in_sizes[2] / EMB;

  unsigned short* us = (unsigned short*)d_ws;
  unsigned short* d1r = us; us += (size_t)D * 32;
  unsigned short* d1c = us; us += (size_t)D * 32;
  unsigned short* d2r = us; us += (size_t)D * 32;
  unsigned short* d2c = us; us += (size_t)D * 32;
  unsigned short* qrA = us; us += (size_t)Q * 32;
  unsigned short* qcA = us; us += (size_t)Q * 32;
  float* fp = (float*)us;
  float* logits   = fp; fp += Q;
  float* partials = fp; fp += (size_t)Q * 4 * 22;

  int grid = (Q >> 8) + 2 * (D >> 8);
  prep_all_kernel<<<grid, 256, 0, stream>>>(qe, d1, d2, Q, D, Wc, bc, qidf, Wqw,
                                            qrA, qcA, d1r, d1c, d2r, d2c, logits);
  main_kernel<<<(Q / 16) * 4, 256, 0, stream>>>(qrA, qcA, d1r, d1c, d2r, d2c, partials, Q, D);
  stage2_final_kernel<<<1, 1024, 0, stream>>>(logits, partials, Wq1, Wq2,
                                              gaf, baf, Wout, (float*)d_out, Q);
}